// Round 9
// baseline (600.166 us; speedup 1.0000x reference)
//
#include <hip/hip_runtime.h>

// VQ-VAE forward on MI355X (gfx950). N=32768 tokens, D=512, M=1024, H=512.
// R15: revert to the verified R9/R10 skeleton (2-barrier counted-vmcnt
// ping-pong, unfused, XCD swizzle) and change ONE thing: wave tile 64x64 ->
// 128x64 (4 waves, 2x2, block 256x128, BK=32). Rationale: R6-R13 all shared
// the 64x64 wave tile -> FLOP/LDS-byte fixed at 32 -> MfmaUtil pinned at
// 21-23% across every other structural change (LDS-traffic-bound). New tile
// raises FLOP/LDS-byte to 43.7 (gemm) / 64 (dist). R14's single-barrier
// recipe reverted (it drained vmcnt(0) ~400cy after issue -> -19%).
// acc[8][4] f32x4 = 128 VGPR; ~190-225 total, 2 waves/SIMD.

#define N_TOK 32768
// s_waitcnt imm: vmcnt low nibble [3:0], expcnt=7 [6:4], lgkmcnt=15 [11:8]
#define WAITV(n) __builtin_amdgcn_s_waitcnt(0x0F70 | (n))
#define BAR() __builtin_amdgcn_s_barrier()

typedef __attribute__((ext_vector_type(8))) short short8;     // 8x16b = 4 VGPR
typedef _Float16 half8 __attribute__((ext_vector_type(8)));
typedef __attribute__((ext_vector_type(4))) float f32x4;

__device__ __forceinline__ f32x4 mfma16(short8 a, short8 b, f32x4 c) {
    return __builtin_amdgcn_mfma_f32_16x16x32_bf16(a, b, c, 0, 0, 0);
}
__device__ __forceinline__ f32x4 mfma16h(half8 a, half8 b, f32x4 c) {
    return __builtin_amdgcn_mfma_f32_16x16x32_f16(a, b, c, 0, 0, 0);
}

__device__ __forceinline__ void gl_lds16(const unsigned short* g, char* l) {
    __builtin_amdgcn_global_load_lds(
        (const __attribute__((address_space(1))) void*)g,
        (__attribute__((address_space(3))) void*)l, 16, 0, 0);
}

__device__ __forceinline__ unsigned short f2bf(float x) {   // RNE fp32->bf16
    unsigned u = __float_as_uint(x);
    u += 0x7fffu + ((u >> 16) & 1u);
    return (unsigned short)(u >> 16);
}
__device__ __forceinline__ float bf2f(unsigned short h) {
    return __uint_as_float(((unsigned)h) << 16);
}
__device__ __forceinline__ unsigned short f2h(float x) {    // RNE fp32->fp16
    union { _Float16 h; unsigned short u; } c;
    c.h = (_Float16)x;
    return c.u;
}
__device__ __forceinline__ float h2f(unsigned short u) {
    union { _Float16 h; unsigned short u; } c;
    c.u = u;
    return (float)c.h;
}

__device__ __forceinline__ float waveSum(float v) {
#pragma unroll
    for (int off = 32; off > 0; off >>= 1) v += __shfl_down(v, off, 64);
    return v;  // lane 0
}
__device__ __forceinline__ float xorSum(float v) {
#pragma unroll
    for (int off = 1; off < 64; off <<= 1) v += __shfl_xor(v, off);
    return v;  // all lanes
}

// ---------------- prep: X -> Xf (fp16) + A1 = bf16(relu(ln1(x))) ----------
__global__ __launch_bounds__(256) void prep_x_kernel(
        const float* __restrict__ X, const float* __restrict__ g,
        const float* __restrict__ b, unsigned short* __restrict__ Xf,
        unsigned short* __restrict__ A1, unsigned long long* __restrict__ minpack) {
    int tid = threadIdx.x;
    if (tid < 4) minpack[(blockIdx.x << 2) + tid] = ~0ULL;
    int lane = tid & 63;
    int n = (blockIdx.x << 2) + (tid >> 6);
    const float* row = X + ((size_t)n << 9);
    float v[8]; float s = 0.f, ss = 0.f;
#pragma unroll
    for (int i = 0; i < 8; ++i) { v[i] = row[lane + (i << 6)]; s += v[i]; ss += v[i] * v[i]; }
    s = xorSum(s); ss = xorSum(ss);
    float mu = s * (1.f / 512.f);
    float rs = rsqrtf(ss * (1.f / 512.f) - mu * mu + 1e-5f);
#pragma unroll
    for (int i = 0; i < 8; ++i) {
        int c = lane + (i << 6);
        size_t o = ((size_t)n << 9) + c;
        float x = v[i];
        Xf[o] = f2h(x);
        float a = fmaxf((x - mu) * rs * g[c] + b[c], 0.f);
        A1[o] = f2bf(a);
    }
}

// ---------------- prep: Hb(bf16) -> A2 = bf16(relu(ln2(h))) ----------------
__global__ __launch_bounds__(256) void prep_h_kernel(
        const unsigned short* __restrict__ Hb, const float* __restrict__ g,
        const float* __restrict__ b, unsigned short* __restrict__ A2) {
    int lane = threadIdx.x & 63;
    int n = (blockIdx.x << 2) + (threadIdx.x >> 6);
    const unsigned short* row = Hb + ((size_t)n << 9);
    float v[8]; float s = 0.f, ss = 0.f;
#pragma unroll
    for (int i = 0; i < 8; ++i) { v[i] = bf2f(row[lane + (i << 6)]); s += v[i]; ss += v[i] * v[i]; }
    s = xorSum(s); ss = xorSum(ss);
    float mu = s * (1.f / 512.f);
    float rs = rsqrtf(ss * (1.f / 512.f) - mu * mu + 1e-5f);
#pragma unroll
    for (int i = 0; i < 8; ++i) {
        int c = lane + (i << 6);
        float a = fmaxf((v[i] - mu) * rs * g[c] + b[c], 0.f);
        A2[((size_t)n << 9) + c] = f2bf(a);
    }
}

// ---------------- prep: E -> Ehf,Elf (fp16, scaled x512) + e_sq*512 --------
__global__ __launch_bounds__(256) void prep_e_kernel(
        const float* __restrict__ E, unsigned short* __restrict__ Ehf,
        unsigned short* __restrict__ Elf, float* __restrict__ e_sq,
        int* __restrict__ izero) {
    if (blockIdx.x < 8) izero[(blockIdx.x << 8) + threadIdx.x] = 0;
    int lane = threadIdx.x & 63;
    int m = (blockIdx.x << 2) + (threadIdx.x >> 6);
    const float* row = E + ((size_t)m << 9);
    float ss = 0.f;
#pragma unroll
    for (int i = 0; i < 8; ++i) {
        int c = lane + (i << 6);
        float x = row[c];
        ss += x * x;
        float xs = x * 512.f;           // exact pow2 scale, dodges fp16 subnormals
        unsigned short h = f2h(xs);
        size_t o = ((size_t)m << 9) + c;
        Ehf[o] = h;
        Elf[o] = f2h(xs - h2f(h));
    }
    ss = xorSum(ss);
    if (lane == 0) e_sq[m] = ss * 512.f;  // scaled to match 512*(x.e)
}

// ---------------- prep: W1 and W2 fp32 -> WT bf16 (one launch) -------------
__global__ __launch_bounds__(256) void prep_wt_kernel(
        const float* __restrict__ W1, const float* __restrict__ W2,
        unsigned short* __restrict__ W1T, unsigned short* __restrict__ W2T) {
    __shared__ float t[32][33];
    int bx = blockIdx.x;
    const float* W = (bx < 16) ? W1 : W2;
    unsigned short* WT = (bx < 16) ? W1T : W2T;
    int Nw = (bx < 16) ? 512 : 1024;
    int n0 = ((bx < 16) ? bx : (bx - 16)) << 5, k0 = blockIdx.y << 5;
    int tx = threadIdx.x & 31, ty = threadIdx.x >> 5;
#pragma unroll
    for (int l = 0; l < 4; ++l)
        t[ty + (l << 3)][tx] = W[(size_t)(k0 + ty + (l << 3)) * Nw + n0 + tx];
    __syncthreads();
#pragma unroll
    for (int l = 0; l < 4; ++l)
        WT[(((size_t)(n0 + ty + (l << 3))) << 9) + k0 + tx] = f2bf(t[tx][ty + (l << 3)]);
}

// ---------------- distance MFMA (fp16 2-pass, wave=128x64, blk 256x128) ----
// LDS/buf 32KB: A[4kb][256][8] (16KB) | Bh[4][128][8] (8KB) | Bl (8KB); x2 dbuf
__device__ __forceinline__ unsigned long long packDist(float d, int m) {
    unsigned u = __float_as_uint(d);
    u = (u & 0x80000000u) ? ~u : (u | 0x80000000u);
    return ((unsigned long long)u << 32) | (unsigned)m;
}

__global__ __launch_bounds__(256) void dist_mfma_kernel(
        const unsigned short* __restrict__ Xf,
        const unsigned short* __restrict__ Ehf, const unsigned short* __restrict__ Elf,
        const float* __restrict__ e_sq, unsigned long long* __restrict__ minpack) {
    __shared__ __align__(16) char LB[65536];
    int tid = threadIdx.x, lane = tid & 63, w = tid >> 6;
    int quad = lane >> 4, lanelo = lane & 15;
    int wm = w >> 1, wn = w & 1;           // 2x2 wave grid; wave tile 128x64
    // XCD swizzle: per-XCD seq s: row-tile(256) = (s>>3)*8 + x, m-chunk = s&7
    int bid = blockIdx.x, x = bid & 7, s = bid >> 3;
    int row0 = (((s >> 3) << 3) | x) << 8;
    int m0 = (s & 7) << 7;

    // staging: thread t stages A row t (4 chunks kb=0..3) and Bh/Bl row t&127
    // (2 chunks kb0=(t>>7)*2, +1). All offsets compile-time under full unroll.
    const unsigned short* pA = Xf  + (((size_t)(row0 + tid)) << 9);
    int nB = tid & 127, kB0 = (tid >> 7) << 1;
    const unsigned short* pH = Ehf + (((size_t)(m0 + nB)) << 9) + (kB0 << 3);
    const unsigned short* pL = Elf + (((size_t)(m0 + nB)) << 9) + (kB0 << 3);
    char* dA  = LB + (tid << 4);                         // + kb*4096
    char* dBh = LB + 16384 + (kB0 << 11) + (nB << 4);    // + {0,2048}
    char* dBl = dBh + 8192;
    const char* ra  = LB + (quad << 12) + (((wm << 7) + lanelo) << 4);
    const char* rbh = LB + 16384 + (quad << 11) + (((wn << 6) + lanelo) << 4);

    f32x4 acc[8][4];
#pragma unroll
    for (int i = 0; i < 8; ++i)
#pragma unroll
        for (int j = 0; j < 4; ++j) acc[i][j] = 0.f;

    // prologue: tile 0 -> buf 0 (8 loads/thread)
    gl_lds16(pA, dA);            gl_lds16(pA + 8, dA + 4096);
    gl_lds16(pA + 16, dA + 8192); gl_lds16(pA + 24, dA + 12288);
    gl_lds16(pH, dBh);           gl_lds16(pH + 8, dBh + 2048);
    gl_lds16(pL, dBl);           gl_lds16(pL + 8, dBl + 2048);

#pragma unroll
    for (int it = 0; it < 16; ++it) {
        const int cb = it & 1;
        if (it < 15) {   // prefetch next tile into other buffer, then wait
            const unsigned short* sA = pA + ((it + 1) << 5);
            const unsigned short* sH = pH + ((it + 1) << 5);
            const unsigned short* sL = pL + ((it + 1) << 5);
            char* eA  = dA  + (cb ^ 1) * 32768;
            char* eBh = dBh + (cb ^ 1) * 32768;
            char* eBl = dBl + (cb ^ 1) * 32768;
            gl_lds16(sA, eA);            gl_lds16(sA + 8, eA + 4096);
            gl_lds16(sA + 16, eA + 8192); gl_lds16(sA + 24, eA + 12288);
            gl_lds16(sH, eBh);           gl_lds16(sH + 8, eBh + 2048);
            gl_lds16(sL, eBl);           gl_lds16(sL + 8, eBl + 2048);
            WAITV(8);    // current tile complete; next tile's 8 stay in flight
        } else {
            WAITV(0);
        }
        BAR();
        const char* A  = ra  + cb * 32768;
        const char* Bh = rbh + cb * 32768;
        half8 av[8], bh[4], bl[4];
#pragma unroll
        for (int i = 0; i < 8; ++i) av[i] = *(const half8*)(A + (i << 8));
#pragma unroll
        for (int j = 0; j < 4; ++j) {
            bh[j] = *(const half8*)(Bh + (j << 8));
            bl[j] = *(const half8*)(Bh + 8192 + (j << 8));
        }
#pragma unroll
        for (int i = 0; i < 8; ++i)
#pragma unroll
            for (int j = 0; j < 4; ++j) acc[i][j] = mfma16h(av[i], bh[j], acc[i][j]);
#pragma unroll
        for (int i = 0; i < 8; ++i)
#pragma unroll
            for (int j = 0; j < 4; ++j) acc[i][j] = mfma16h(av[i], bl[j], acc[i][j]);
        BAR();  // all waves done reading buf cb before it is restaged
    }

    float esq[4];
#pragma unroll
    for (int j = 0; j < 4; ++j) esq[j] = e_sq[m0 + (wn << 6) + (j << 4) + lanelo];
#pragma unroll
    for (int i = 0; i < 8; ++i)
#pragma unroll
        for (int r = 0; r < 4; ++r) {
            unsigned long long best = ~0ULL;
#pragma unroll
            for (int j = 0; j < 4; ++j) {
                int code = m0 + (wn << 6) + (j << 4) + lanelo;
                float d = esq[j] - 2.f * acc[i][j][r];
                unsigned long long p = packDist(d, code);
                if (p < best) best = p;
            }
#pragma unroll
            for (int off = 1; off < 16; off <<= 1) {
                unsigned long long q2 = __shfl_xor(best, off);
                if (q2 < best) best = q2;
            }
            if (lanelo == 0) {
                int t = row0 + (wm << 7) + (i << 4) + (quad << 2) + r;
                atomicMin(&minpack[t], best);
            }
        }
}

// ---------------- GEMM core: wave=128x64, blk 256x128, BK=32, ping-pong ----
// LDS/buf 24KB: A[4kb][256][8] (16KB) | B[4][128][8] (8KB); x2 dbuf = 48KB
__device__ __forceinline__ void gemm_core(
        char* LB, const unsigned short* pA, const unsigned short* pB,
        char* dBbase, f32x4 (*acc)[4]) {
    int tid = threadIdx.x, lane = tid & 63, w = tid >> 6;
    int quad = lane >> 4, lanelo = lane & 15;
    int wm = w >> 1, wn = w & 1;
    char* dA = LB + (tid << 4);
    char* dB = dBbase;
    const char* ra = LB + (quad << 12) + (((wm << 7) + lanelo) << 4);
    const char* rb = LB + 16384 + (quad << 11) + (((wn << 6) + lanelo) << 4);

    gl_lds16(pA, dA);            gl_lds16(pA + 8, dA + 4096);
    gl_lds16(pA + 16, dA + 8192); gl_lds16(pA + 24, dA + 12288);
    gl_lds16(pB, dB);            gl_lds16(pB + 8, dB + 2048);

#pragma unroll
    for (int it = 0; it < 16; ++it) {
        const int cb = it & 1;
        if (it < 15) {
            const unsigned short* sA = pA + ((it + 1) << 5);
            const unsigned short* sB = pB + ((it + 1) << 5);
            char* eA = dA + (cb ^ 1) * 24576;
            char* eB = dB + (cb ^ 1) * 24576;
            gl_lds16(sA, eA);            gl_lds16(sA + 8, eA + 4096);
            gl_lds16(sA + 16, eA + 8192); gl_lds16(sA + 24, eA + 12288);
            gl_lds16(sB, eB);            gl_lds16(sB + 8, eB + 2048);
            WAITV(6);    // current tile complete; next tile's 6 in flight
        } else {
            WAITV(0);
        }
        BAR();
        const char* A = ra + cb * 24576;
        const char* B = rb + cb * 24576;
        short8 af[8], bf4[4];
#pragma unroll
        for (int i = 0; i < 8; ++i) af[i] = *(const short8*)(A + (i << 8));
#pragma unroll
        for (int j = 0; j < 4; ++j) bf4[j] = *(const short8*)(B + (j << 8));
#pragma unroll
        for (int i = 0; i < 8; ++i)
#pragma unroll
            for (int j = 0; j < 4; ++j) acc[i][j] = mfma16(af[i], bf4[j], acc[i][j]);
        BAR();
    }
}

// ---------------- GEMM1: Hb = bf16(A1 @ W1T^T), 512 blocks x 256 -----------
__global__ __launch_bounds__(256) void gemm1_mfma_kernel(
        const unsigned short* __restrict__ A1, const unsigned short* __restrict__ W1T,
        unsigned short* __restrict__ Hb) {
    __shared__ __align__(16) char LB[49152];
    int tid = threadIdx.x, lane = tid & 63, w = tid >> 6;
    int quad = lane >> 4, lanelo = lane & 15;
    int wm = w >> 1, wn = w & 1;
    // per-XCD seq s (0..63): row-tile(256) = (s>>2)*8 + x, n-chunk = s&3
    int bid = blockIdx.x, x = bid & 7, s = bid >> 3;
    int row0 = (((s >> 2) << 3) | x) << 8;
    int n0 = (s & 3) << 7;

    const unsigned short* pA = A1 + (((size_t)(row0 + tid)) << 9);
    int nB = tid & 127, kB0 = (tid >> 7) << 1;
    const unsigned short* pB = W1T + (((size_t)(n0 + nB)) << 9) + (kB0 << 3);
    char* dB = LB + 16384 + (kB0 << 11) + (nB << 4);

    f32x4 acc[8][4];
#pragma unroll
    for (int i = 0; i < 8; ++i)
#pragma unroll
        for (int j = 0; j < 4; ++j) acc[i][j] = 0.f;

    gemm_core(LB, pA, pB, dB, acc);

#pragma unroll
    for (int i = 0; i < 8; ++i)
#pragma unroll
        for (int j = 0; j < 4; ++j)
#pragma unroll
            for (int r = 0; r < 4; ++r) {
                int row = row0 + (wm << 7) + (i << 4) + (quad << 2) + r;
                int col = n0 + (wn << 6) + (j << 4) + lanelo;
                Hb[((size_t)row << 9) + col] = f2bf(acc[i][j][r]);
            }
}

// ---------------- GEMM2 + softmax partials, 1024 blocks x 256 --------------
__global__ __launch_bounds__(256) void gemm2_chunk_kernel(
        const unsigned short* __restrict__ A2, const unsigned short* __restrict__ W2T,
        const int* __restrict__ mask, const int* __restrict__ labels,
        float* __restrict__ ws_cmax, float* __restrict__ ws_csum,
        float* __restrict__ ws_lab) {
    __shared__ __align__(16) char LB[49152];
    __shared__ float lmax[2][2][128], lsum[2][2][128], llab[256];
    __shared__ int slab[256];
    int tid = threadIdx.x, lane = tid & 63, w = tid >> 6;
    int quad = lane >> 4, lanelo = lane & 15;
    int wm = w >> 1, wn = w & 1;
    // per-XCD seq s (0..127): row-tile(256) = (s>>3)*8 + x, c-chunk = s&7
    int bid = blockIdx.x, x = bid & 7, s = bid >> 3;
    int row0 = (((s >> 3) << 3) | x) << 8;
    int cy = s & 7;
    int c0 = cy << 7;
    {
        int mk = mask[row0 + tid];
        slab[tid] = mk ? 0 : labels[row0 + tid];
    }
    __syncthreads();

    const unsigned short* pA = A2 + (((size_t)(row0 + tid)) << 9);
    int nB = tid & 127, kB0 = (tid >> 7) << 1;
    const unsigned short* pB = W2T + (((size_t)(c0 + nB)) << 9) + (kB0 << 3);
    char* dB = LB + 16384 + (kB0 << 11) + (nB << 4);

    f32x4 acc[8][4];
#pragma unroll
    for (int i = 0; i < 8; ++i)
#pragma unroll
        for (int j = 0; j < 4; ++j) acc[i][j] = 0.f;

    gemm_core(LB, pA, pB, dB, acc);

    // label-logit capture (unique owner lane/reg)
#pragma unroll
    for (int i = 0; i < 8; ++i)
#pragma unroll
        for (int j = 0; j < 4; ++j)
#pragma unroll
            for (int r = 0; r < 4; ++r) {
                int code = c0 + (wn << 6) + (j << 4) + lanelo;
                int tt = (wm << 7) + (i << 4) + (quad << 2) + r;
                if (code == slab[tt]) llab[tt] = acc[i][j][r];
            }
#pragma unroll
    for (int i = 0; i < 8; ++i)
#pragma unroll
        for (int r = 0; r < 4; ++r) {
            float mx = fmaxf(fmaxf(acc[i][0][r], acc[i][1][r]),
                             fmaxf(acc[i][2][r], acc[i][3][r]));
#pragma unroll
            for (int off = 1; off < 16; off <<= 1) mx = fmaxf(mx, __shfl_xor(mx, off));
            if (lanelo == 0) lmax[wm][wn][(i << 4) + (quad << 2) + r] = mx;
        }
    __syncthreads();
#pragma unroll
    for (int i = 0; i < 8; ++i)
#pragma unroll
        for (int r = 0; r < 4; ++r) {
            int tl = (i << 4) + (quad << 2) + r;
            float cm = fmaxf(lmax[wm][0][tl], lmax[wm][1][tl]);
            float s2 = expf(acc[i][0][r] - cm) + expf(acc[i][1][r] - cm) +
                       expf(acc[i][2][r] - cm) + expf(acc[i][3][r] - cm);
#pragma unroll
            for (int off = 1; off < 16; off <<= 1) s2 += __shfl_xor(s2, off);
            if (lanelo == 0) lsum[wm][wn][tl] = s2;
        }
    __syncthreads();
    {
        int wmi = tid >> 7, tl = tid & 127;
        int token = row0 + tid;
        float cm = fmaxf(lmax[wmi][0][tl], lmax[wmi][1][tl]);
        float cs = lsum[wmi][0][tl] + lsum[wmi][1][tl];
        size_t o = ((size_t)cy << 15) + token;  // [chunk][token]
        ws_cmax[o] = cm;
        ws_csum[o] = cs;
        if ((slab[tid] >> 7) == cy) ws_lab[token] = llab[tid];
    }
}

// ---------------- gather quantized + int counts + vq term ----------------
__global__ __launch_bounds__(256) void gather_kernel(
        const float* __restrict__ X, const float* __restrict__ E,
        const unsigned long long* __restrict__ minpack,
        float* __restrict__ out_q, int* __restrict__ icounts,
        float* __restrict__ vqsum) {
    int lane = threadIdx.x & 63;
    int n = (blockIdx.x << 2) + (threadIdx.x >> 6);
    int idx = (int)(minpack[n] & 0xFFFFFFFFULL);
    if (lane == 0) atomicAdd(&icounts[idx], 1);
    const float* xr = X + ((size_t)n << 9);
    const float* er = E + ((size_t)idx << 9);
    float s = 0.f;
#pragma unroll
    for (int i = 0; i < 8; ++i) {
        int c = lane + (i << 6);
        float xv = xr[c], q = er[c];
        out_q[((size_t)n << 9) + c] = q;
        float dlt = xv - q;
        s += dlt * dlt;
    }
    s = waveSum(s);
    if (lane == 0) vqsum[n] = 0.25f * s;
}

// ---------------- codebook: EMA smoothing + perplexity + bucket offsets ----
__global__ __launch_bounds__(1024) void codebook_kernel(
        const float* __restrict__ ema_count, const int* __restrict__ icounts,
        float* __restrict__ out_perp, float* __restrict__ out_newcount,
        int* __restrict__ offsets) {
    __shared__ int sc[1024];
    __shared__ float red[16];
    int tid = threadIdx.x;
    int lane = tid & 63, wid = tid >> 6;
    int ic = icounts[tid];
    sc[tid] = ic;
    for (int off = 1; off < 1024; off <<= 1) {
        __syncthreads();
        int v = (tid >= off) ? sc[tid - off] : 0;
        __syncthreads();
        sc[tid] += v;
    }
    offsets[tid] = sc[tid] - ic;
    __syncthreads();

    float cnt = (float)ic;
    float raw = 0.999f * ema_count[tid] + 0.001f * cnt;
    float v = waveSum(raw);
    if (lane == 0) red[wid] = v;
    __syncthreads();
    float nsum = 0.f;
#pragma unroll
    for (int i = 0; i < 16; ++i) nsum += red[i];
    __syncthreads();
    float p = cnt * (1.f / 32768.f);
    float e = p * logf(p + 1e-10f);
    e = waveSum(e);
    if (lane == 0) red[wid] = e;
    __syncthreads();
    float ent = 0.f;
#pragma unroll
    for (int i = 0; i < 16; ++i) ent += red[i];
    float nc = (raw + 1e-5f) / (nsum + 1024.f * 1e-5f) * nsum;
    out_newcount[tid] = nc;
    if (tid == 0) out_perp[0] = expf(-ent);
}

// ---------------- scatter: token n -> bucket of its code ----------------
__global__ __launch_bounds__(256) void scatter_kernel(
        const unsigned long long* __restrict__ minpack,
        const int* __restrict__ offsets, int* __restrict__ cursor,
        int* __restrict__ bucket) {
    int n = (blockIdx.x << 8) + threadIdx.x;
    int idx = (int)(minpack[n] & 0xFFFFFFFFULL);
    int pos = atomicAdd(&cursor[idx], 1);
    bucket[offsets[idx] + pos] = n;
}

// ---------------- dw[m] = sum of x rows in bucket m (dense reads) ----------
__global__ __launch_bounds__(256) void dw_kernel(
        const float* __restrict__ X, const int* __restrict__ bucket,
        const int* __restrict__ icounts, const int* __restrict__ offsets,
        float* __restrict__ dw) {
    __shared__ float comb[4][512];
    int tid = threadIdx.x, lane = tid & 63, w = tid >> 6;
    int m = blockIdx.x;
    int cnt = icounts[m], base = offsets[m];
    float acc[8] = {};
    for (int i = w; i < cnt; i += 4) {
        int t = bucket[base + i];
        const float* xr = X + ((size_t)t << 9);
#pragma unroll
        for (int j = 0; j < 8; ++j) acc[j] += xr[lane + (j << 6)];
    }
#pragma unroll
    for (int j = 0; j < 8; ++j) comb[w][lane + (j << 6)] = acc[j];
    __syncthreads();
    for (int c = tid; c < 512; c += 256)
        dw[((size_t)m << 9) + c] = comb[0][c] + comb[1][c] + comb[2][c] + comb[3][c];
}

// ---------------- epilogue: new_weight/new_embedding + CE combine ----------
__global__ __launch_bounds__(256) void epilogue_kernel(
        const float* __restrict__ ema_weight, const float* __restrict__ dw,
        const float* __restrict__ newcount, float* __restrict__ out_neww,
        float* __restrict__ out_newemb,
        const float* __restrict__ ws_cmax, const float* __restrict__ ws_csum,
        const float* __restrict__ ws_lab, const int* __restrict__ mask,
        const float* __restrict__ vqsum, float* __restrict__ loss_out) {
    int bx = blockIdx.x;
    if (bx < 2048) {
        int i = (bx << 8) + threadIdx.x;
        float nw = 0.999f * ema_weight[i] + 0.001f * dw[i];
        out_neww[i] = nw;
        out_newemb[i] = nw / newcount[i >> 9];
    } else {
        int n = ((bx - 2048) << 8) + threadIdx.x;
        float m[8], s[8];
#pragma unroll
        for (int c = 0; c < 8; ++c) {
            m[c] = ws_cmax[(c << 15) + n];
            s[c] = ws_csum[(c << 15) + n];
        }
        float gm = m[0];
#pragma unroll
        for (int c = 1; c < 8; ++c) gm = fmaxf(gm, m[c]);
        float se = 0.f;
#pragma unroll
        for (int c = 0; c < 8; ++c) se += s[c] * expf(m[c] - gm);
        float ce = -(ws_lab[n] - gm - logf(se));
        loss_out[n] = (mask[n] ? 0.f : ce) + vqsum[n];
    }
}

extern "C" void kernel_launch(void* const* d_in, const int* in_sizes, int n_in,
                              void* d_out, int out_size, void* d_ws, size_t ws_size,
                              hipStream_t stream) {
    const float* X          = (const float*)d_in[0];
    const int*   mask       = (const int*)d_in[1];
    const int*   labels     = (const int*)d_in[2];
    const float* E          = (const float*)d_in[3];
    const float* ema_count  = (const float*)d_in[4];
    const float* ema_weight = (const float*)d_in[5];
    const float* g1 = (const float*)d_in[6];
    const float* b1 = (const float*)d_in[7];
    const float* W1 = (const float*)d_in[8];
    const float* g2 = (const float*)d_in[9];
    const float* b2 = (const float*)d_in[10];
    const float* W2 = (const float*)d_in[11];

    float* out = (float*)d_out;
    float* out_q        = out;              // 16777216
    float* out_loss     = out + 16777216;   // 32768
    float* out_perp     = out + 16809984;   // 1
    float* out_newemb   = out + 16809985;   // 524288
    float* out_newcount = out + 17334273;   // 1024
    float* out_neww     = out + 17335297;   // 524288

    float* w = (float*)d_ws;
    float* vqsum = w;  w += 32768;
    float* e_sq = w;   w += 1024;
    float* dwbuf = w;  w += 524288;
    unsigned long long* minpack = (unsigned long long*)w; w += 65536;
    float* ws_cmax = w; w += 262144;
    float* ws_csum = w; w += 262144;
    float* ws_lab  = w; w += 32768;
    int* icounts = (int*)w; w += 1024;      // icounts+cursor contiguous zero region
    int* cursor  = (int*)w; w += 1024;
    int* offsets = (int*)w; w += 1024;
    int* bucket  = (int*)w; w += 32768;
    unsigned short* Ehf = (unsigned short*)w; w += 262144;
    unsigned short* Elf = (unsigned short*)w; w += 262144;
    unsigned short* W1T = (unsigned short*)w; w += 131072;
    unsigned short* W2T = (unsigned short*)w; w += 262144;
    unsigned short* Xf  = (unsigned short*)w; w += 8388608;
    unsigned short* A1  = (unsigned short*)w; w += 8388608;
    unsigned short* Hb  = (unsigned short*)w; w += 8388608;
    unsigned short* A2  = Xf;   // alias: Xf dead after dist

    prep_e_kernel<<<256, 256, 0, stream>>>(E, Ehf, Elf, e_sq, icounts);
    prep_wt_kernel<<<dim3(48, 16), 256, 0, stream>>>(W1, W2, W1T, W2T);
    prep_x_kernel<<<8192, 256, 0, stream>>>(X, g1, b1, Xf, A1, minpack);
    dist_mfma_kernel<<<1024, 256, 0, stream>>>(Xf, Ehf, Elf, e_sq, minpack);
    gather_kernel<<<8192, 256, 0, stream>>>(X, E, minpack, out_q, icounts, vqsum);
    codebook_kernel<<<1, 1024, 0, stream>>>(ema_count, icounts, out_perp,
                                            out_newcount, offsets);
    scatter_kernel<<<128, 256, 0, stream>>>(minpack, offsets, cursor, bucket);
    dw_kernel<<<1024, 256, 0, stream>>>(X, bucket, icounts, offsets, dwbuf);
    gemm1_mfma_kernel<<<512, 256, 0, stream>>>(A1, W1T, Hb);
    prep_h_kernel<<<8192, 256, 0, stream>>>(Hb, g2, b2, A2);
    gemm2_chunk_kernel<<<1024, 256, 0, stream>>>(A2, W2T, mask, labels,
                                                 ws_cmax, ws_csum, ws_lab);
    epilogue_kernel<<<2176, 256, 0, stream>>>(ema_weight, dwbuf, out_newcount,
                                              out_neww, out_newemb,
                                              ws_cmax, ws_csum, ws_lab,
                                              mask, vqsum, out_loss);
}

// Round 10
// 469.382 us; speedup vs baseline: 1.2786x; 1.2786x over previous
//
#include <hip/hip_runtime.h>

// VQ-VAE forward on MI355X (gfx950). N=32768 tokens, D=512, M=1024, H=512.
// R16: zero-new-structure assembly of the best HARNESS-VERIFIED pieces:
//   - fused1 (dist 256x128 512-thr + gemm1, co-scheduled, 2-barrier counted
//     vmcnt, XCD swizzle) = 161us measured in R13
//   - gemm2 @ BK=64 (2-barrier counted WAITV(8)) = <128us measured in R10
//   - fused2 (gather + prep_h interleaved) verified R11-R13
//   - prep/codebook/scatter/dw/epilogue = R9 verbatim
// R15 post-mortem: 128-wide wave tile -> VGPR 168 -> occupancy 11.5%,
// MfmaUtil 6.3% (register cliff swamps arithmetic-intensity gain). R14
// post-mortem: single-barrier recipe drains vmcnt(0) ~400cy after issue
// (guide: "never drain vmcnt in main loop") -> both reverted.

#define N_TOK 32768
// s_waitcnt imm: vmcnt low nibble [3:0], expcnt=7 [6:4], lgkmcnt=15 [11:8]
#define WAITV(n) __builtin_amdgcn_s_waitcnt(0x0F70 | (n))
#define BAR() __builtin_amdgcn_s_barrier()

typedef __attribute__((ext_vector_type(8))) short short8;     // 8x16b = 4 VGPR
typedef _Float16 half8 __attribute__((ext_vector_type(8)));
typedef __attribute__((ext_vector_type(4))) float f32x4;

__device__ __forceinline__ f32x4 mfma16(short8 a, short8 b, f32x4 c) {
    return __builtin_amdgcn_mfma_f32_16x16x32_bf16(a, b, c, 0, 0, 0);
}
__device__ __forceinline__ f32x4 mfma16h(half8 a, half8 b, f32x4 c) {
    return __builtin_amdgcn_mfma_f32_16x16x32_f16(a, b, c, 0, 0, 0);
}

__device__ __forceinline__ void gl_lds16(const unsigned short* g, char* l) {
    __builtin_amdgcn_global_load_lds(
        (const __attribute__((address_space(1))) void*)g,
        (__attribute__((address_space(3))) void*)l, 16, 0, 0);
}

__device__ __forceinline__ unsigned short f2bf(float x) {   // RNE fp32->bf16
    unsigned u = __float_as_uint(x);
    u += 0x7fffu + ((u >> 16) & 1u);
    return (unsigned short)(u >> 16);
}
__device__ __forceinline__ float bf2f(unsigned short h) {
    return __uint_as_float(((unsigned)h) << 16);
}
__device__ __forceinline__ unsigned short f2h(float x) {    // RNE fp32->fp16
    union { _Float16 h; unsigned short u; } c;
    c.h = (_Float16)x;
    return c.u;
}
__device__ __forceinline__ float h2f(unsigned short u) {
    union { _Float16 h; unsigned short u; } c;
    c.u = u;
    return (float)c.h;
}

__device__ __forceinline__ float waveSum(float v) {
#pragma unroll
    for (int off = 32; off > 0; off >>= 1) v += __shfl_down(v, off, 64);
    return v;  // lane 0
}
__device__ __forceinline__ float xorSum(float v) {
#pragma unroll
    for (int off = 1; off < 64; off <<= 1) v += __shfl_xor(v, off);
    return v;  // all lanes
}

// ---------------- prep: X -> Xf (fp16) + A1 = bf16(relu(ln1(x))) ----------
__global__ __launch_bounds__(256) void prep_x_kernel(
        const float* __restrict__ X, const float* __restrict__ g,
        const float* __restrict__ b, unsigned short* __restrict__ Xf,
        unsigned short* __restrict__ A1, unsigned long long* __restrict__ minpack) {
    int tid = threadIdx.x;
    if (tid < 4) minpack[(blockIdx.x << 2) + tid] = ~0ULL;
    int lane = tid & 63;
    int n = (blockIdx.x << 2) + (tid >> 6);
    const float* row = X + ((size_t)n << 9);
    float v[8]; float s = 0.f, ss = 0.f;
#pragma unroll
    for (int i = 0; i < 8; ++i) { v[i] = row[lane + (i << 6)]; s += v[i]; ss += v[i] * v[i]; }
    s = xorSum(s); ss = xorSum(ss);
    float mu = s * (1.f / 512.f);
    float rs = rsqrtf(ss * (1.f / 512.f) - mu * mu + 1e-5f);
#pragma unroll
    for (int i = 0; i < 8; ++i) {
        int c = lane + (i << 6);
        size_t o = ((size_t)n << 9) + c;
        float x = v[i];
        Xf[o] = f2h(x);
        float a = fmaxf((x - mu) * rs * g[c] + b[c], 0.f);
        A1[o] = f2bf(a);
    }
}

// ---------------- prep: E -> Ehf,Elf (fp16, scaled x512) + e_sq*512 --------
__global__ __launch_bounds__(256) void prep_e_kernel(
        const float* __restrict__ E, unsigned short* __restrict__ Ehf,
        unsigned short* __restrict__ Elf, float* __restrict__ e_sq,
        int* __restrict__ izero) {
    if (blockIdx.x < 8) izero[(blockIdx.x << 8) + threadIdx.x] = 0;
    int lane = threadIdx.x & 63;
    int m = (blockIdx.x << 2) + (threadIdx.x >> 6);
    const float* row = E + ((size_t)m << 9);
    float ss = 0.f;
#pragma unroll
    for (int i = 0; i < 8; ++i) {
        int c = lane + (i << 6);
        float x = row[c];
        ss += x * x;
        float xs = x * 512.f;           // exact pow2 scale, dodges fp16 subnormals
        unsigned short h = f2h(xs);
        size_t o = ((size_t)m << 9) + c;
        Ehf[o] = h;
        Elf[o] = f2h(xs - h2f(h));
    }
    ss = xorSum(ss);
    if (lane == 0) e_sq[m] = ss * 512.f;  // scaled to match 512*(x.e)
}

// ---------------- prep: W1 and W2 fp32 -> WT bf16 (one launch) -------------
__global__ __launch_bounds__(256) void prep_wt_kernel(
        const float* __restrict__ W1, const float* __restrict__ W2,
        unsigned short* __restrict__ W1T, unsigned short* __restrict__ W2T) {
    __shared__ float t[32][33];
    int bx = blockIdx.x;
    const float* W = (bx < 16) ? W1 : W2;
    unsigned short* WT = (bx < 16) ? W1T : W2T;
    int Nw = (bx < 16) ? 512 : 1024;
    int n0 = ((bx < 16) ? bx : (bx - 16)) << 5, k0 = blockIdx.y << 5;
    int tx = threadIdx.x & 31, ty = threadIdx.x >> 5;
#pragma unroll
    for (int l = 0; l < 4; ++l)
        t[ty + (l << 3)][tx] = W[(size_t)(k0 + ty + (l << 3)) * Nw + n0 + tx];
    __syncthreads();
#pragma unroll
    for (int l = 0; l < 4; ++l)
        WT[(((size_t)(n0 + ty + (l << 3))) << 9) + k0 + tx] = f2bf(t[tx][ty + (l << 3)]);
}

// ---------------- distance body (fp16 2-pass, BM=256/BN=128/BK=32) ---------
// R13-verified. LDS/buf 32KB: A[4kb][256][8] | Bh[4][128][8] | Bl; x2 dbuf
__device__ __forceinline__ unsigned long long packDist(float d, int m) {
    unsigned u = __float_as_uint(d);
    u = (u & 0x80000000u) ? ~u : (u | 0x80000000u);
    return ((unsigned long long)u << 32) | (unsigned)m;
}

__device__ __forceinline__ void dist_body(
        int q, int x, char* LB,
        const unsigned short* __restrict__ Xf,
        const unsigned short* __restrict__ Ehf, const unsigned short* __restrict__ Elf,
        const float* __restrict__ e_sq, unsigned long long* __restrict__ minpack) {
    int tid = threadIdx.x, lane = tid & 63, w = tid >> 6;
    int quad = lane >> 4, lanelo = lane & 15;
    int wm = w >> 1, wn = w & 1;           // 4x2 wave grid, wave = 64x64
    // per-XCD seq q (0..127): row-tile(256) = (q>>3)*8 + x, m-chunk = q&7
    int row0 = (((q >> 3) << 3) | x) << 8;
    int m0 = (q & 7) << 7;

    // staging: thread t -> A chunks (kb=t>>8, m=t&255) + (kb+2, m); B (t>>7, t&127)
    int mA = tid & 255, kA = tid >> 8;
    int nB = tid & 127, kB = tid >> 7;
    const unsigned short* pA = Xf  + (((size_t)(row0 + mA)) << 9) + (kA << 3);
    const unsigned short* pH = Ehf + (((size_t)(m0  + nB)) << 9) + (kB << 3);
    const unsigned short* pL = Elf + (((size_t)(m0  + nB)) << 9) + (kB << 3);
    char* dA = LB + (tid << 4);
    char* dB = LB + 16384 + (tid << 4);
    const char* ra  = LB + (quad << 12) + (((wm << 6) + lanelo) << 4);
    const char* rbh = LB + 16384 + (quad << 11) + (((wn << 6) + lanelo) << 4);

    f32x4 acc[4][4];
#pragma unroll
    for (int i = 0; i < 4; ++i)
#pragma unroll
        for (int j = 0; j < 4; ++j) acc[i][j] = 0.f;

    // prologue: tile 0 -> buf 0 (4 loads/thread)
    gl_lds16(pA, dA);   gl_lds16(pA + 16, dA + 8192);
    gl_lds16(pH, dB);   gl_lds16(pL, dB + 8192);

#pragma unroll
    for (int it = 0; it < 16; ++it) {
        const int cb = it & 1;
        if (it < 15) {
            const unsigned short* sA = pA + ((it + 1) << 5);
            const unsigned short* sH = pH + ((it + 1) << 5);
            const unsigned short* sL = pL + ((it + 1) << 5);
            char* eA = dA + (cb ^ 1) * 32768;
            char* eB = dB + (cb ^ 1) * 32768;
            gl_lds16(sA, eA);   gl_lds16(sA + 16, eA + 8192);
            gl_lds16(sH, eB);   gl_lds16(sL, eB + 8192);
            WAITV(4);    // current tile complete; next tile in flight
        } else {
            WAITV(0);
        }
        BAR();
        const char* A  = ra  + cb * 32768;
        const char* Bh = rbh + cb * 32768;
        half8 av[4], bh[4], bl[4];
#pragma unroll
        for (int i = 0; i < 4; ++i) av[i] = *(const half8*)(A + (i << 8));
#pragma unroll
        for (int j = 0; j < 4; ++j) {
            bh[j] = *(const half8*)(Bh + (j << 8));
            bl[j] = *(const half8*)(Bh + 8192 + (j << 8));
        }
#pragma unroll
        for (int i = 0; i < 4; ++i)
#pragma unroll
            for (int j = 0; j < 4; ++j) acc[i][j] = mfma16h(av[i], bh[j], acc[i][j]);
#pragma unroll
        for (int i = 0; i < 4; ++i)
#pragma unroll
            for (int j = 0; j < 4; ++j) acc[i][j] = mfma16h(av[i], bl[j], acc[i][j]);
        BAR();  // all waves done reading buf cb before restage (at it+1)
    }

    float esq[4];
#pragma unroll
    for (int j = 0; j < 4; ++j) esq[j] = e_sq[m0 + (wn << 6) + (j << 4) + lanelo];
#pragma unroll
    for (int i = 0; i < 4; ++i)
#pragma unroll
        for (int r = 0; r < 4; ++r) {
            unsigned long long best = ~0ULL;
#pragma unroll
            for (int j = 0; j < 4; ++j) {
                int code = m0 + (wn << 6) + (j << 4) + lanelo;
                float d = esq[j] - 2.f * acc[i][j][r];
                unsigned long long p = packDist(d, code);
                if (p < best) best = p;
            }
#pragma unroll
            for (int off = 1; off < 16; off <<= 1) {
                unsigned long long q2 = __shfl_xor(best, off);
                if (q2 < best) best = q2;
            }
            if (lanelo == 0) {
                int t = row0 + (wm << 6) + (i << 4) + (quad << 2) + r;
                atomicMin(&minpack[t], best);
            }
        }
}

// ---------------- GEMM core: BM=256/BN=128/BK=32, bf16, ping-pong ----------
// R13-verified. LDS/buf 24KB: A[4kb][256][8] (16KB) | B[4][128][8] (8KB)
__device__ __forceinline__ void gemm_core512(
        char* LB, const unsigned short* pA, const unsigned short* pB,
        f32x4 (*acc)[4]) {
    int tid = threadIdx.x, lane = tid & 63, w = tid >> 6;
    int quad = lane >> 4, lanelo = lane & 15;
    int wm = w >> 1, wn = w & 1;
    char* dA = LB + (tid << 4);
    char* dB = LB + 16384 + (tid << 4);
    const char* ra = LB + (quad << 12) + (((wm << 6) + lanelo) << 4);
    const char* rb = LB + 16384 + (quad << 11) + (((wn << 6) + lanelo) << 4);

    gl_lds16(pA, dA);   gl_lds16(pA + 16, dA + 8192);
    gl_lds16(pB, dB);

#pragma unroll
    for (int it = 0; it < 16; ++it) {
        const int cb = it & 1;
        if (it < 15) {
            const unsigned short* sA = pA + ((it + 1) << 5);
            const unsigned short* sB = pB + ((it + 1) << 5);
            char* eA = dA + (cb ^ 1) * 24576;
            char* eB = dB + (cb ^ 1) * 24576;
            gl_lds16(sA, eA);   gl_lds16(sA + 16, eA + 8192);
            gl_lds16(sB, eB);
            WAITV(3);
        } else {
            WAITV(0);
        }
        BAR();
        const char* A = ra + cb * 24576;
        const char* B = rb + cb * 24576;
        short8 af[4], bf4[4];
#pragma unroll
        for (int i = 0; i < 4; ++i) af[i] = *(const short8*)(A + (i << 8));
#pragma unroll
        for (int j = 0; j < 4; ++j) bf4[j] = *(const short8*)(B + (j << 8));
#pragma unroll
        for (int i = 0; i < 4; ++i)
#pragma unroll
            for (int j = 0; j < 4; ++j) acc[i][j] = mfma16(af[i], bf4[j], acc[i][j]);
        BAR();
    }
}

// ---------------- GEMM1 body: Hb = bf16(A1 @ W1T^T) ------------------------
__device__ __forceinline__ void gemm1_body(
        int g, int x, char* LB,
        const unsigned short* __restrict__ A1, const unsigned short* __restrict__ W1T,
        unsigned short* __restrict__ Hb) {
    int tid = threadIdx.x, lane = tid & 63, w = tid >> 6;
    int quad = lane >> 4, lanelo = lane & 15;
    int wm = w >> 1, wn = w & 1;
    // per-XCD seq g (0..63): row-tile(256) = (g>>2)*8 + x, n-chunk = g&3
    int row0 = (((g >> 2) << 3) | x) << 8;
    int n0 = (g & 3) << 7;

    int mA = tid & 255, kA = tid >> 8;
    int nB = tid & 127, kB = tid >> 7;
    const unsigned short* pA = A1  + (((size_t)(row0 + mA)) << 9) + (kA << 3);
    const unsigned short* pB = W1T + (((size_t)(n0   + nB)) << 9) + (kB << 3);

    f32x4 acc[4][4];
#pragma unroll
    for (int i = 0; i < 4; ++i)
#pragma unroll
        for (int j = 0; j < 4; ++j) acc[i][j] = 0.f;

    gemm_core512(LB, pA, pB, acc);

#pragma unroll
    for (int i = 0; i < 4; ++i)
#pragma unroll
        for (int j = 0; j < 4; ++j)
#pragma unroll
            for (int r = 0; r < 4; ++r) {
                int row = row0 + (wm << 6) + (i << 4) + (quad << 2) + r;
                int col = n0 + (wn << 6) + (j << 4) + lanelo;
                Hb[((size_t)row << 9) + col] = f2bf(acc[i][j][r]);
            }
}

// ---------------- fused1: dist(1024) + gemm1(512), 1536 blocks x 512 -------
__global__ __launch_bounds__(512) void fused1_kernel(
        const unsigned short* __restrict__ Xf,
        const unsigned short* __restrict__ Ehf, const unsigned short* __restrict__ Elf,
        const float* __restrict__ e_sq, unsigned long long* __restrict__ minpack,
        const unsigned short* __restrict__ A1, const unsigned short* __restrict__ W1T,
        unsigned short* __restrict__ Hb) {
    __shared__ __align__(16) char LB[65536];   // dist 64KB; gemm1 uses 48KB
    int b = blockIdx.x, x = b & 7, m = b >> 3;
    int t = m % 3, g = m / 3;   // per XCD: {dist,dist,gemm1} repeating
    if (t < 2) dist_body((g << 1) + t, x, LB, Xf, Ehf, Elf, e_sq, minpack);
    else       gemm1_body(g, x, LB, A1, W1T, Hb);
}

// ---------------- fused2: gather(8192) + prep_h(8192), 16384 blocks --------
__global__ __launch_bounds__(256) void fused2_kernel(
        const float* __restrict__ X, const float* __restrict__ E,
        const unsigned long long* __restrict__ minpack,
        float* __restrict__ out_q, int* __restrict__ icounts,
        float* __restrict__ vqsum,
        const unsigned short* __restrict__ Hb, const float* __restrict__ g2,
        const float* __restrict__ b2, unsigned short* __restrict__ A2) {
    int nb = blockIdx.x >> 1;
    int lane = threadIdx.x & 63;
    int n = (nb << 2) + (threadIdx.x >> 6);
    if ((blockIdx.x & 1) == 0) {
        // gather
        int idx = (int)(minpack[n] & 0xFFFFFFFFULL);
        if (lane == 0) atomicAdd(&icounts[idx], 1);
        const float* xr = X + ((size_t)n << 9);
        const float* er = E + ((size_t)idx << 9);
        float s = 0.f;
#pragma unroll
        for (int i = 0; i < 8; ++i) {
            int c = lane + (i << 6);
            float xv = xr[c], q = er[c];
            out_q[((size_t)n << 9) + c] = q;
            float dlt = xv - q;
            s += dlt * dlt;
        }
        s = waveSum(s);
        if (lane == 0) vqsum[n] = 0.25f * s;
    } else {
        // prep_h
        const unsigned short* row = Hb + ((size_t)n << 9);
        float v[8]; float s = 0.f, ss = 0.f;
#pragma unroll
        for (int i = 0; i < 8; ++i) { v[i] = bf2f(row[lane + (i << 6)]); s += v[i]; ss += v[i] * v[i]; }
        s = xorSum(s); ss = xorSum(ss);
        float mu = s * (1.f / 512.f);
        float rs = rsqrtf(ss * (1.f / 512.f) - mu * mu + 1e-5f);
#pragma unroll
        for (int i = 0; i < 8; ++i) {
            int c = lane + (i << 6);
            float a = fmaxf((v[i] - mu) * rs * g2[c] + b2[c], 0.f);
            A2[((size_t)n << 9) + c] = f2bf(a);
        }
    }
}

// ---------------- codebook: EMA smoothing + perplexity + bucket offsets ----
__global__ __launch_bounds__(1024) void codebook_kernel(
        const float* __restrict__ ema_count, const int* __restrict__ icounts,
        float* __restrict__ out_perp, float* __restrict__ out_newcount,
        int* __restrict__ offsets) {
    __shared__ int sc[1024];
    __shared__ float red[16];
    int tid = threadIdx.x;
    int lane = tid & 63, wid = tid >> 6;
    int ic = icounts[tid];
    sc[tid] = ic;
    for (int off = 1; off < 1024; off <<= 1) {
        __syncthreads();
        int v = (tid >= off) ? sc[tid - off] : 0;
        __syncthreads();
        sc[tid] += v;
    }
    offsets[tid] = sc[tid] - ic;
    __syncthreads();

    float cnt = (float)ic;
    float raw = 0.999f * ema_count[tid] + 0.001f * cnt;
    float v = waveSum(raw);
    if (lane == 0) red[wid] = v;
    __syncthreads();
    float nsum = 0.f;
#pragma unroll
    for (int i = 0; i < 16; ++i) nsum += red[i];
    __syncthreads();
    float p = cnt * (1.f / 32768.f);
    float e = p * logf(p + 1e-10f);
    e = waveSum(e);
    if (lane == 0) red[wid] = e;
    __syncthreads();
    float ent = 0.f;
#pragma unroll
    for (int i = 0; i < 16; ++i) ent += red[i];
    float nc = (raw + 1e-5f) / (nsum + 1024.f * 1e-5f) * nsum;
    out_newcount[tid] = nc;
    if (tid == 0) out_perp[0] = expf(-ent);
}

// ---------------- scatter: token n -> bucket of its code ----------------
__global__ __launch_bounds__(256) void scatter_kernel(
        const unsigned long long* __restrict__ minpack,
        const int* __restrict__ offsets, int* __restrict__ cursor,
        int* __restrict__ bucket) {
    int n = (blockIdx.x << 8) + threadIdx.x;
    int idx = (int)(minpack[n] & 0xFFFFFFFFULL);
    int pos = atomicAdd(&cursor[idx], 1);
    bucket[offsets[idx] + pos] = n;
}

// ---------------- dw[m] = sum of x rows in bucket m (dense reads) ----------
__global__ __launch_bounds__(256) void dw_kernel(
        const float* __restrict__ X, const int* __restrict__ bucket,
        const int* __restrict__ icounts, const int* __restrict__ offsets,
        float* __restrict__ dw) {
    __shared__ float comb[4][512];
    int tid = threadIdx.x, lane = tid & 63, w = tid >> 6;
    int m = blockIdx.x;
    int cnt = icounts[m], base = offsets[m];
    float acc[8] = {};
    for (int i = w; i < cnt; i += 4) {
        int t = bucket[base + i];
        const float* xr = X + ((size_t)t << 9);
#pragma unroll
        for (int j = 0; j < 8; ++j) acc[j] += xr[lane + (j << 6)];
    }
#pragma unroll
    for (int j = 0; j < 8; ++j) comb[w][lane + (j << 6)] = acc[j];
    __syncthreads();
    for (int c = tid; c < 512; c += 256)
        dw[((size_t)m << 9) + c] = comb[0][c] + comb[1][c] + comb[2][c] + comb[3][c];
}

// ---------------- GEMM2 chunk (R10 exact: BK=64 ping-pong) + softmax -------
__global__ __launch_bounds__(256) void gemm2_chunk_kernel(
        const unsigned short* __restrict__ A2, const unsigned short* __restrict__ W2T,
        const int* __restrict__ mask, const int* __restrict__ labels,
        float* __restrict__ ws_cmax, float* __restrict__ ws_csum,
        float* __restrict__ ws_lab) {
    __shared__ __align__(16) short L[2][2][8192];   // 64 KB
    __shared__ float lmax[2][2][64], lsum[2][2][64], llab[128];
    __shared__ int slab[128];
    int tid = threadIdx.x, lane = tid & 63, w = tid >> 6;
    int quad = lane >> 4, lanelo = lane & 15;
    int wm = w >> 1, wn = w & 1;
    // XCD-locality swizzle: 8 c-chunks of one row-tile consecutive on one XCD.
    int bid = blockIdx.x, xcd = bid & 7, s = bid >> 3;
    int row0 = (((s >> 3) << 3) | xcd) << 7;
    int cy = s & 7;
    int c0 = cy << 7;
    if (tid < 128) {
        int mk = mask[row0 + tid];
        slab[tid] = mk ? 0 : labels[row0 + tid];  // safe label
    }
    __syncthreads();   // slab visible before loop

    int srow = ((w & 1) << 6) + lane;
    int skoff = (w >> 1) << 5;
    const unsigned short* pA = A2  + (((size_t)(row0 + srow)) << 9) + skoff;
    const unsigned short* pB = W2T + (((size_t)(c0   + srow)) << 9) + skoff;
    char* ldsB = (char*)&L[0][0][0] + ((w >> 1) << 13) + ((w & 1) << 10) + (lane << 4);
    const char* ra = (const char*)&L[0][0][0] + (quad << 11) + (((wm << 6) + lanelo) << 4);
    const char* rb = (const char*)&L[0][0][0] + 16384 + (quad << 11) + (((wn << 6) + lanelo) << 4);

    f32x4 acc[4][4];
#pragma unroll
    for (int i = 0; i < 4; ++i)
#pragma unroll
        for (int j = 0; j < 4; ++j) acc[i][j] = 0.f;

    gl_lds16(pA, ldsB);           gl_lds16(pA + 8, ldsB + 2048);
    gl_lds16(pA + 16, ldsB + 4096); gl_lds16(pA + 24, ldsB + 6144);
    gl_lds16(pB, ldsB + 16384);   gl_lds16(pB + 8, ldsB + 18432);
    gl_lds16(pB + 16, ldsB + 20480); gl_lds16(pB + 24, ldsB + 22528);

#pragma unroll
    for (int it = 0; it < 8; ++it) {
        const int cb = it & 1;
        if (it < 7) {
            const unsigned short* sA = pA + ((it + 1) << 6);
            const unsigned short* sB = pB + ((it + 1) << 6);
            char* d = ldsB + (cb ^ 1) * 32768;
            gl_lds16(sA, d);           gl_lds16(sA + 8, d + 2048);
            gl_lds16(sA + 16, d + 4096); gl_lds16(sA + 24, d + 6144);
            gl_lds16(sB, d + 16384);   gl_lds16(sB + 8, d + 18432);
            gl_lds16(sB + 16, d + 20480); gl_lds16(sB + 24, d + 22528);
            WAITV(8);
        } else {
            WAITV(0);
        }
        BAR();
        const char* A = ra + cb * 32768;
        const char* B = rb + cb * 32768;
#pragma unroll
        for (int kk = 0; kk < 2; ++kk) {
            short8 af[4], bf4[4];
#pragma unroll
            for (int i = 0; i < 4; ++i) af[i] = *(const short8*)(A + (kk << 13) + (i << 8));
#pragma unroll
            for (int j = 0; j < 4; ++j) bf4[j] = *(const short8*)(B + (kk << 13) + (j << 8));
#pragma unroll
            for (int i = 0; i < 4; ++i)
#pragma unroll
                for (int j = 0; j < 4; ++j) acc[i][j] = mfma16(af[i], bf4[j], acc[i][j]);
        }
        BAR();
    }

    // label-logit capture (unique owner lane/reg)
#pragma unroll
    for (int i = 0; i < 4; ++i)
#pragma unroll
        for (int j = 0; j < 4; ++j)
#pragma unroll
            for (int r = 0; r < 4; ++r) {
                int code = c0 + (wn << 6) + (j << 4) + lanelo;
                int tt = (wm << 6) + (i << 4) + (quad << 2) + r;
                if (code == slab[tt]) llab[tt] = acc[i][j][r];
            }
#pragma unroll
    for (int i = 0; i < 4; ++i)
#pragma unroll
        for (int r = 0; r < 4; ++r) {
            float mx = fmaxf(fmaxf(acc[i][0][r], acc[i][1][r]),
                             fmaxf(acc[i][2][r], acc[i][3][r]));
#pragma unroll
            for (int off = 1; off < 16; off <<= 1) mx = fmaxf(mx, __shfl_xor(mx, off));
            if (lanelo == 0) lmax[wm][wn][(i << 4) + (quad << 2) + r] = mx;
        }
    __syncthreads();
#pragma unroll
    for (int i = 0; i < 4; ++i)
#pragma unroll
        for (int r = 0; r < 4; ++r) {
            int tl = (i << 4) + (quad << 2) + r;
            float cm = fmaxf(lmax[wm][0][tl], lmax[wm][1][tl]);
            float s2 = expf(acc[i][0][r] - cm) + expf(acc[i][1][r] - cm) +
                       expf(acc[i][2][r] - cm) + expf(acc[i][3][r] - cm);
#pragma unroll
            for (int off = 1; off < 16; off <<= 1) s2 += __shfl_xor(s2, off);
            if (lanelo == 0) lsum[wm][wn][tl] = s2;
        }
    __syncthreads();
    if (tid < 128) {
        int wmi = tid >> 6, tl = tid & 63;
        int token = row0 + tid;
        float cm = fmaxf(lmax[wmi][0][tl], lmax[wmi][1][tl]);
        float cs = lsum[wmi][0][tl] + lsum[wmi][1][tl];
        size_t o = ((size_t)cy << 15) + token;  // [chunk][token]
        ws_cmax[o] = cm;
        ws_csum[o] = cs;
        if ((slab[tid] >> 7) == cy) ws_lab[token] = llab[tid];
    }
}

// ---------------- epilogue: new_weight/new_embedding + CE combine ----------
__global__ __launch_bounds__(256) void epilogue_kernel(
        const float* __restrict__ ema_weight, const float* __restrict__ dw,
        const float* __restrict__ newcount, float* __restrict__ out_neww,
        float* __restrict__ out_newemb,
        const float* __restrict__ ws_cmax, const float* __restrict__ ws_csum,
        const float* __restrict__ ws_lab, const int* __restrict__ mask,
        const float* __restrict__ vqsum, float* __restrict__ loss_out) {
    int bx = blockIdx.x;
    if (bx < 2048) {
        int i = (bx << 8) + threadIdx.x;
        float nw = 0.999f * ema_weight[i] + 0.001f * dw[i];
        out_neww[i] = nw;
        out_newemb[i] = nw / newcount[i >> 9];
    } else {
        int n = ((bx - 2048) << 8) + threadIdx.x;
        float m[8], s[8];
#pragma unroll
        for (int c = 0; c < 8; ++c) {
            m[c] = ws_cmax[(c << 15) + n];
            s[c] = ws_csum[(c << 15) + n];
        }
        float gm = m[0];
#pragma unroll
        for (int c = 1; c < 8; ++c) gm = fmaxf(gm, m[c]);
        float se = 0.f;
#pragma unroll
        for (int c = 0; c < 8; ++c) se += s[c] * expf(m[c] - gm);
        float ce = -(ws_lab[n] - gm - logf(se));
        loss_out[n] = (mask[n] ? 0.f : ce) + vqsum[n];
    }
}

extern "C" void kernel_launch(void* const* d_in, const int* in_sizes, int n_in,
                              void* d_out, int out_size, void* d_ws, size_t ws_size,
                              hipStream_t stream) {
    const float* X          = (const float*)d_in[0];
    const int*   mask       = (const int*)d_in[1];
    const int*   labels     = (const int*)d_in[2];
    const float* E          = (const float*)d_in[3];
    const float* ema_count  = (const float*)d_in[4];
    const float* ema_weight = (const float*)d_in[5];
    const float* g1 = (const float*)d_in[6];
    const float* b1 = (const float*)d_in[7];
    const float* W1 = (const float*)d_in[8];
    const float* g2 = (const float*)d_in[9];
    const float* b2 = (const float*)d_in[10];
    const float* W2 = (const float*)d_in[11];

    float* out = (float*)d_out;
    float* out_q        = out;              // 16777216
    float* out_loss     = out + 16777216;   // 32768
    float* out_perp     = out + 16809984;   // 1
    float* out_newemb   = out + 16809985;   // 524288
    float* out_newcount = out + 17334273;   // 1024
    float* out_neww     = out + 17335297;   // 524288

    float* w = (float*)d_ws;
    float* vqsum = w;  w += 32768;
    float* e_sq = w;   w += 1024;
    float* dwbuf = w;  w += 524288;
    unsigned long long* minpack = (unsigned long long*)w; w += 65536;
    float* ws_cmax = w; w += 262144;
    float* ws_csum = w; w += 262144;
    float* ws_lab  = w; w += 32768;
    int* icounts = (int*)w; w += 1024;      // icounts+cursor contiguous zero region
    int* cursor  = (int*)w; w += 1024;
    int* offsets = (int*)w; w += 1024;
    int* bucket  = (int*)w; w += 32768;
    unsigned short* Ehf = (unsigned short*)w; w += 262144;
    unsigned short* Elf = (unsigned short*)w; w += 262144;
    unsigned short* W1T = (unsigned short*)w; w += 131072;
    unsigned short* W2T = (unsigned short*)w; w += 262144;
    unsigned short* Xf  = (unsigned short*)w; w += 8388608;
    unsigned short* A1  = (unsigned short*)w; w += 8388608;
    unsigned short* Hb  = (unsigned short*)w; w += 8388608;
    unsigned short* A2  = Xf;   // alias: Xf dead after dist

    prep_e_kernel<<<256, 256, 0, stream>>>(E, Ehf, Elf, e_sq, icounts);
    prep_wt_kernel<<<dim3(48, 16), 256, 0, stream>>>(W1, W2, W1T, W2T);
    prep_x_kernel<<<8192, 256, 0, stream>>>(X, g1, b1, Xf, A1, minpack);
    fused1_kernel<<<1536, 512, 0, stream>>>(Xf, Ehf, Elf, e_sq, minpack,
                                            A1, W1T, Hb);
    fused2_kernel<<<16384, 256, 0, stream>>>(X, E, minpack, out_q, icounts,
                                             vqsum, Hb, g2, b2, A2);
    codebook_kernel<<<1, 1024, 0, stream>>>(ema_count, icounts, out_perp,
                                            out_newcount, offsets);
    scatter_kernel<<<128, 256, 0, stream>>>(minpack, offsets, cursor, bucket);
    dw_kernel<<<1024, 256, 0, stream>>>(X, bucket, icounts, offsets, dwbuf);
    gemm2_chunk_kernel<<<2048, 256, 0, stream>>>(A2, W2T, mask, labels,
                                                 ws_cmax, ws_csum, ws_lab);
    epilogue_kernel<<<2176, 256, 0, stream>>>(ema_weight, dwbuf, out_newcount,
                                              out_neww, out_newemb,
                                              ws_cmax, ws_csum, ws_lab,
                                              mask, vqsum, out_loss);
}